// Round 7
// baseline (677.662 us; speedup 1.0000x reference)
//
#include <hip/hip_runtime.h>
#include <math.h>

#define HW 16384
#define EPSC 1.00001f   // 1 + 1e-5

typedef short bf16x8 __attribute__((ext_vector_type(8)));
typedef float f32x4 __attribute__((ext_vector_type(4)));
typedef float f32x16 __attribute__((ext_vector_type(16)));

static __device__ __forceinline__ unsigned short f2bf(float f) {
    unsigned int u = __float_as_uint(f);
    unsigned int r = (u + 0x7fffu + ((u >> 16) & 1u)) >> 16;
    return (unsigned short)r;
}
static __device__ __forceinline__ float bf2f(unsigned short u) {
    return __uint_as_float(((unsigned int)u) << 16);
}

// ---------------- mean over H*W (per (b,c) plane, f32 NCHW) ----------------
__global__ void mean_hw_kernel(const float* __restrict__ x, float* __restrict__ out) {
    int blk = blockIdx.x;
    const float4* p4 = (const float4*)(x + (size_t)blk * HW);
    float s = 0.f;
    for (int i = threadIdx.x; i < HW / 4; i += 256) {
        float4 v = p4[i];
        s += v.x + v.y + v.z + v.w;
    }
    for (int off = 32; off > 0; off >>= 1) s += __shfl_down(s, off, 64);
    __shared__ float red[4];
    int lane = threadIdx.x & 63, wid = threadIdx.x >> 6;
    if (lane == 0) red[wid] = s;
    __syncthreads();
    if (threadIdx.x == 0)
        out[blk] = (red[0] + red[1] + red[2] + red[3]) * (1.0f / (float)HW);
}

// ---------------- convva[b,co] = sum_ci conv_w[co,ci]*va[b,ci] ----------------
__global__ void convva_kernel(const float* __restrict__ va, const float* __restrict__ cw,
                              float* __restrict__ out) {
    int t = threadIdx.x;           // 512 = 8*64
    int b = t >> 6, co = t & 63;
    float s = 0.f;
    for (int ci = 0; ci < 128; ci++) s = fmaf(cw[co * 128 + ci], va[b * 128 + ci], s);
    out[t] = s;
}

// ---------------- partial mean of att0 (bf16 NHWC) ----------------
__global__ void att_mean_part(const unsigned short* __restrict__ att0, float* __restrict__ part) {
    int s = blockIdx.x, b = blockIdx.y;
    int c = threadIdx.x & 63, pr = threadIdx.x >> 6;
    const unsigned short* p = att0 + ((size_t)b * HW + s * 1024 + pr * 256) * 64 + c;
    float acc = 0.f;
    for (int i = 0; i < 256; i++) acc += bf2f(p[(size_t)i * 64]);
    __shared__ float red[4][64];
    red[pr][c] = acc;
    __syncthreads();
    if (threadIdx.x < 64)
        part[(b * 16 + s) * 64 + threadIdx.x] =
            red[0][threadIdx.x] + red[1][threadIdx.x] + red[2][threadIdx.x] + red[3][threadIdx.x];
}

// ---------------- SE MLP (from partials) ----------------
__global__ void se_mlp_kernel(const float* __restrict__ part, const float* __restrict__ w1,
                              const float* __restrict__ w2, float* __restrict__ scale) {
    __shared__ float t[8][4];
    __shared__ float ym[8][64];
    int tid = threadIdx.x;         // 512
    {
        int b = tid >> 6, c = tid & 63;
        float s = 0.f;
        for (int i = 0; i < 16; i++) s += part[(b * 16 + i) * 64 + c];
        ym[b][c] = s * (1.0f / (float)HW);
    }
    __syncthreads();
    if (tid < 32) {
        int b = tid >> 2, h = tid & 3;
        float s = 0.f;
        for (int ci = 0; ci < 64; ci++) s = fmaf(ym[b][ci], w1[h * 64 + ci], s);
        t[b][h] = s >= 0.f ? s : 0.01f * s;
    }
    __syncthreads();
    int b = tid >> 6, c = tid & 63;
    float s = 0.f;
    for (int h = 0; h < 4; h++) s = fmaf(t[b][h], w2[c * 4 + h], s);
    scale[b * 64 + c] = 1.0f / (1.0f + __expf(-s));
}

// kse bilinear (align-corners): k table is 25 floats for (b,c)
__device__ __forceinline__ float kse_val(const float* kt, int y, int x) {
    float ys = y * (4.0f / 127.0f);
    int y0 = (int)ys; if (y0 > 4) y0 = 4;
    int y1 = min(y0 + 1, 4);
    float wy = ys - (float)y0;
    float xs = x * (4.0f / 127.0f);
    int x0 = (int)xs; if (x0 > 4) x0 = 4;
    int x1 = min(x0 + 1, 4);
    float wx = xs - (float)x0;
    float r0 = kt[y0 * 5 + x0] * (1.f - wx) + kt[y0 * 5 + x1] * wx;
    float r1 = kt[y1 * 5 + x0] * (1.f - wx) + kt[y1 * 5 + x1] * wx;
    return r0 * (1.f - wy) + r1 * wy;
}

// ---------------- repack x1 f32 NCHW[128][HW] -> two bf16 NHWC [HW][64] ----------------
__global__ void repack_x1_kernel(const float* __restrict__ x1,
                                 unsigned short* __restrict__ xa,
                                 unsigned short* __restrict__ xb) {
    __shared__ float t[64][65];
    int b = blockIdx.y;
    int p0 = blockIdx.x * 64;
    for (int h = 0; h < 2; ++h) {
        const float* src = x1 + ((size_t)b * 128 + h * 64) * HW + p0;
        __syncthreads();
        for (int e = threadIdx.x; e < 4096; e += 256) {
            int ci = e >> 6, px = e & 63;
            t[ci][px] = src[(size_t)ci * HW + px];
        }
        __syncthreads();
        unsigned short* dst = (h == 0 ? xa : xb) + ((size_t)b * HW + p0) * 64;
        for (int e = threadIdx.x; e < 4096; e += 256) {
            int px = e >> 6, ci = e & 63;
            dst[(size_t)px * 64 + ci] = f2bf(t[ci][px]);
        }
    }
}

// ---------------- weight pack (triple 1x1): [co][ci] f32 -> [ch][co_total][32] bf16 ----------------
__global__ void prep_w_kernel(const float* __restrict__ src, unsigned short* __restrict__ dst,
                              int CO, int CI, int K, int co_total, int co_off) {
    int idx = blockIdx.x * 256 + threadIdx.x;
    int total = CO * CI * K * K;
    if (idx >= total) return;
    int kx = idx % K, t1 = idx / K;
    int ky = t1 % K, t2 = t1 / K;
    int ci = t2 % CI, co = t2 / CI;
    int tap = ky * K + kx, chunk = ci >> 5, k32 = ci & 31;
    int kc = tap * (CI >> 5) + chunk;
    dst[((size_t)kc * co_total + co_off + co) * 32 + k32] = f2bf(src[idx]);
}

// ---------------- weight pack for 32x32 MFMA (CI=64): lane-contiguous slabs ----------------
// slab(tap) = [kstep(4)][mb(2)][lane(64)][8], lane = khalf*32 + (co&31)
__global__ void prep_w32_kernel(const float* __restrict__ src, unsigned short* __restrict__ dst,
                                int CO, int CI, int K) {
    int idx = blockIdx.x * 256 + threadIdx.x;
    int total = CO * CI * K * K;
    if (idx >= total) return;
    int kx = idx % K, t1 = idx / K;
    int ky = t1 % K, t2 = t1 / K;
    int ci = t2 % CI, co = t2 / CI;
    int tap = ky * K + kx;
    int kstep = ci >> 4, khalf = (ci >> 3) & 1, j = ci & 7;
    int l = khalf * 32 + (co & 31), mb = co >> 5;
    dst[(((size_t)(tap * 4 + kstep) * 2 + mb) * 64 + l) * 8 + j] = f2bf(src[idx]);
}

// ---------------- weight pack for 16x16 MFMA 1x1 (CI=128): lane-contiguous ----------------
// [ch(4)][mb(4)][lane(64)][8], lane = q*16 + (co&15)
__global__ void prep_w16_kernel(const float* __restrict__ src, unsigned short* __restrict__ dst,
                                int CO, int CI) {
    int idx = blockIdx.x * 256 + threadIdx.x;
    if (idx >= CO * CI) return;
    int ci = idx % CI, co = idx / CI;
    int ch = ci >> 5, q = (ci >> 3) & 3, j = ci & 7;
    int l = q * 16 + (co & 15), mb = co >> 4;
    dst[(((size_t)ch * 4 + mb) * 64 + l) * 8 + j] = f2bf(src[idx]);
}

// ---------------- 32x32x16 MFMA implicit conv (CI=64, 16x16 px tile, 64co) ----------------
// Wave: 64co x 64px (2 mb x 2 nt MFMAs/kstep).  W slabs relayed global->reg->LDS per tap.
// emode: 0=bnlrelu  1=sigmoid(bnlrelu)  2=bnlrelu*(1+kse)
//        4=bnlrelu->out_bf; aux_bf=eB*v   5=bnlrelu+eB+eC->out_bf   6=sigmoid(bnlrelu)*eB
template<int KSZ>
__global__ __launch_bounds__(256, 2) void conv_mfma32(
    const unsigned short* __restrict__ Xa,
    const unsigned short* __restrict__ Wp,
    const float* __restrict__ g, const float* __restrict__ bb,
    const float* __restrict__ kk,
    const unsigned short* __restrict__ eB, const unsigned short* __restrict__ eC,
    unsigned short* __restrict__ out_bf, unsigned short* __restrict__ aux_bf, int emode)
{
    constexpr int PAD = KSZ / 2;
    constexpr int TWX = 16 + 2 * PAD;
    constexpr int TWY = 16 + 2 * PAD;
    constexpr int NTAP = KSZ * KSZ;
    constexpr int WSLAB = 4 * 2 * 64 * 8;         // shorts per tap slab (8 KB)
    __shared__ unsigned short xs[TWY * TWX * 64];
    __shared__ unsigned short ws[2 * WSLAB];

    const int b = blockIdx.y;
    const int ty = (blockIdx.x >> 3) * 16, tx = (blockIdx.x & 7) * 16;
    const int tid = threadIdx.x;
    const int lane = tid & 63, wv = tid >> 6;
    const int n32 = lane & 31, khalf = lane >> 5;

    // per-lane output pixel coords (2 N-tiles)
    int rr[2], cc2[2];
#pragma unroll
    for (int nt = 0; nt < 2; ++nt) {
        int p = wv * 64 + nt * 32 + n32;
        rr[nt] = p >> 4; cc2[nt] = p & 15;
    }

    // ---- prefetch W tap 0 ----
    uint4 wst[2];
    {
        const uint4* gw = (const uint4*)Wp;
#pragma unroll
        for (int s = 0; s < 2; ++s) wst[s] = gw[tid + s * 256];
    }
    // ---- stage X tile (swizzled 8-short groups) ----
    for (int e = tid; e < TWY * TWX * 8; e += 256) {
        int ci8 = e & 7, pxl = e >> 3;
        int xx = pxl % TWX, yy = pxl / TWX;
        int gy = ty + yy - PAD, gx = tx + xx - PAD;
        uint4 v = {0u, 0u, 0u, 0u};
        if (gy >= 0 && gy < 128 && gx >= 0 && gx < 128)
            v = *(const uint4*)(Xa + (((size_t)b * HW + gy * 128 + gx) * 64 + ci8 * 8));
        *(uint4*)(&xs[(size_t)pxl * 64 + ((ci8 ^ (pxl & 7)) << 3)]) = v;
    }
    // ---- write W tap 0 ----
    {
        uint4* lw = (uint4*)ws;
#pragma unroll
        for (int s = 0; s < 2; ++s) lw[tid + s * 256] = wst[s];
    }
    __syncthreads();

    f32x16 acc[2][2];
#pragma unroll
    for (int mb = 0; mb < 2; ++mb)
#pragma unroll
        for (int nt = 0; nt < 2; ++nt)
#pragma unroll
            for (int i = 0; i < 16; ++i) acc[mb][nt][i] = 0.f;

    for (int tap = 0; tap < NTAP; ++tap) {
        if (tap + 1 < NTAP) {
            const uint4* gw = (const uint4*)Wp + (size_t)(tap + 1) * (WSLAB / 8);
#pragma unroll
            for (int s = 0; s < 2; ++s) wst[s] = gw[tid + s * 256];
        }
        const unsigned short* wl = ws + (tap & 1) * WSLAB;
        const int ky = tap / KSZ, kx = tap - ky * KSZ;
        int pxl0 = (rr[0] + ky) * TWX + cc2[0] + kx;
        int pxl1 = (rr[1] + ky) * TWX + cc2[1] + kx;
        int sw0 = (pxl0 & 7), sw1 = (pxl1 & 7);
#pragma unroll
        for (int kstep = 0; kstep < 4; ++kstep) {
            bf16x8 af0 = *(const bf16x8*)(wl + ((kstep * 2 + 0) * 64 + lane) * 8);
            bf16x8 af1 = *(const bf16x8*)(wl + ((kstep * 2 + 1) * 64 + lane) * 8);
            int gidx = kstep * 2 + khalf;
            bf16x8 b0 = *(const bf16x8*)(&xs[(size_t)pxl0 * 64 + ((gidx ^ sw0) << 3)]);
            bf16x8 b1 = *(const bf16x8*)(&xs[(size_t)pxl1 * 64 + ((gidx ^ sw1) << 3)]);
            acc[0][0] = __builtin_amdgcn_mfma_f32_32x32x16_bf16(af0, b0, acc[0][0], 0, 0, 0);
            acc[0][1] = __builtin_amdgcn_mfma_f32_32x32x16_bf16(af0, b1, acc[0][1], 0, 0, 0);
            acc[1][0] = __builtin_amdgcn_mfma_f32_32x32x16_bf16(af1, b0, acc[1][0], 0, 0, 0);
            acc[1][1] = __builtin_amdgcn_mfma_f32_32x32x16_bf16(af1, b1, acc[1][1], 0, 0, 0);
        }
        if (tap + 1 < NTAP) {
            uint4* lw = (uint4*)(ws + ((tap + 1) & 1) * WSLAB);
#pragma unroll
            for (int s = 0; s < 2; ++s) lw[tid + s * 256] = wst[s];
            __syncthreads();
        }
    }

    // ---- epilogue.  D: col(px)=lane&31, row(co)=(reg&3)+8*(reg>>2)+4*(lane>>5) ----
    const float rs = rsqrtf(EPSC);
#pragma unroll
    for (int mb = 0; mb < 2; ++mb) {
#pragma unroll
        for (int nt = 0; nt < 2; ++nt) {
            const int py = ty + rr[nt];
            const int px = tx + cc2[nt];
            const size_t pix = (size_t)b * HW + py * 128 + px;
#pragma unroll
            for (int rq = 0; rq < 4; ++rq) {
                const int co0 = mb * 32 + rq * 8 + khalf * 4;
                float v4[4];
#pragma unroll
                for (int rg = 0; rg < 4; ++rg) {
                    int co = co0 + rg;
                    float v = acc[mb][nt][rq * 4 + rg];
                    v = fmaf(v, g[co] * rs, bb[co]);
                    v = v >= 0.f ? v : 0.01f * v;
                    if (emode == 1 || emode == 6) v = 1.0f / (1.0f + __expf(-v));
                    else if (emode == 2)
                        v *= (1.0f + kse_val(kk + (size_t)(b * 64 + co) * 25, py, px));
                    v4[rg] = v;
                }
                if (emode == 6) {
                    ushort4 e = *(const ushort4*)(eB + pix * 64 + co0);
                    *(ushort4*)(out_bf + pix * 64 + co0) = (ushort4){
                        f2bf(v4[0] * bf2f(e.x)), f2bf(v4[1] * bf2f(e.y)),
                        f2bf(v4[2] * bf2f(e.z)), f2bf(v4[3] * bf2f(e.w))};
                } else if (emode == 4) {
                    *(ushort4*)(out_bf + pix * 64 + co0) =
                        (ushort4){f2bf(v4[0]), f2bf(v4[1]), f2bf(v4[2]), f2bf(v4[3])};
                    ushort4 e = *(const ushort4*)(eB + pix * 64 + co0);
                    *(ushort4*)(aux_bf + pix * 64 + co0) = (ushort4){
                        f2bf(v4[0] * bf2f(e.x)), f2bf(v4[1] * bf2f(e.y)),
                        f2bf(v4[2] * bf2f(e.z)), f2bf(v4[3] * bf2f(e.w))};
                } else if (emode == 5) {
                    ushort4 e1 = *(const ushort4*)(eB + pix * 64 + co0);
                    ushort4 e2 = *(const ushort4*)(eC + pix * 64 + co0);
                    *(ushort4*)(out_bf + pix * 64 + co0) = (ushort4){
                        f2bf(v4[0] + bf2f(e1.x) + bf2f(e2.x)),
                        f2bf(v4[1] + bf2f(e1.y) + bf2f(e2.y)),
                        f2bf(v4[2] + bf2f(e1.z) + bf2f(e2.z)),
                        f2bf(v4[3] + bf2f(e1.w) + bf2f(e2.w))};
                } else {
                    *(ushort4*)(out_bf + pix * 64 + co0) =
                        (ushort4){f2bf(v4[0]), f2bf(v4[1]), f2bf(v4[2]), f2bf(v4[3])};
                }
            }
        }
    }
}

// ---------------- 16x16x32 MFMA 1x1 conv over concat (CI=128) -> 64co, bnlrelu ----------------
__global__ __launch_bounds__(256, 2) void conv_mfma1x1(
    const unsigned short* __restrict__ Xa, const unsigned short* __restrict__ Xb,
    const unsigned short* __restrict__ Wp,
    const float* __restrict__ g, const float* __restrict__ bb,
    unsigned short* __restrict__ out_bf)
{
    constexpr int CI = 128;
    __shared__ unsigned short xs[128 * CI];       // 8x16 px tile
    __shared__ unsigned short ws[4 * 4 * 64 * 8]; // 16 KB, lane-contiguous
    const int b = blockIdx.y;
    const int ty = (blockIdx.x >> 3) * 8, tx = (blockIdx.x & 7) * 16;
    const int tid = threadIdx.x;
    const int lane = tid & 63, wv = tid >> 6;
    const int n = lane & 15, quad = lane >> 4;

    {
        const uint4* gw = (const uint4*)Wp;
        uint4* lw = (uint4*)ws;
#pragma unroll
        for (int s = 0; s < 4; ++s) lw[tid + s * 256] = gw[tid + s * 256];
    }
    for (int e = tid; e < 128 * 16; e += 256) {
        int ci8 = e & 15, pxl = e >> 4;
        int gy = ty + (pxl >> 4), gx = tx + (pxl & 15);
        const unsigned short* src = (ci8 >= 8) ? Xb : Xa;
        int c8 = ci8 & 7;
        uint4 v = *(const uint4*)(src + (((size_t)b * HW + gy * 128 + gx) * 64 + c8 * 8));
        *(uint4*)(&xs[(size_t)pxl * CI + ((ci8 ^ (pxl & 7)) << 3)]) = v;
    }
    __syncthreads();

    f32x4 acc[4][2];
#pragma unroll
    for (int mb = 0; mb < 4; ++mb)
#pragma unroll
        for (int nt = 0; nt < 2; ++nt) acc[mb][nt] = (f32x4){0.f, 0.f, 0.f, 0.f};

    const int r0 = wv * 2;
#pragma unroll
    for (int ch = 0; ch < 4; ++ch) {
        bf16x8 bfr[2];
#pragma unroll
        for (int nt = 0; nt < 2; ++nt) {
            int pxl = (r0 + nt) * 16 + n;
            bfr[nt] = *(const bf16x8*)(&xs[(size_t)pxl * CI +
                                           (((ch * 4 + quad) ^ (pxl & 7)) << 3)]);
        }
#pragma unroll
        for (int mb = 0; mb < 4; ++mb) {
            bf16x8 af = *(const bf16x8*)(ws + ((ch * 4 + mb) * 64 + lane) * 8);
#pragma unroll
            for (int nt = 0; nt < 2; ++nt)
                acc[mb][nt] = __builtin_amdgcn_mfma_f32_16x16x32_bf16(
                    af, bfr[nt], acc[mb][nt], 0, 0, 0);
        }
    }

    const float rs = rsqrtf(EPSC);
#pragma unroll
    for (int mb = 0; mb < 4; ++mb) {
#pragma unroll
        for (int nt = 0; nt < 2; ++nt) {
            const int py = ty + r0 + nt, px = tx + n;
            const size_t pix = (size_t)b * HW + py * 128 + px;
            const int co0 = mb * 16 + quad * 4;
            float v4[4];
#pragma unroll
            for (int rg = 0; rg < 4; ++rg) {
                float v = fmaf(acc[mb][nt][rg], g[co0 + rg] * rs, bb[co0 + rg]);
                v4[rg] = v >= 0.f ? v : 0.01f * v;
            }
            *(ushort4*)(out_bf + pix * 64 + co0) =
                (ushort4){f2bf(v4[0]), f2bf(v4[1]), f2bf(v4[2]), f2bf(v4[3])};
        }
    }
}

// ---------------- merged 1x1 triple: conv_w/conv1_w/conv2_w over x1 in one pass ----------------
__global__ __launch_bounds__(256, 2) void conv1x1_triple(
    const unsigned short* __restrict__ Xa, const unsigned short* __restrict__ Xb,
    const unsigned short* __restrict__ Wp,
    const float* __restrict__ cva, const float* __restrict__ cbias,
    const float* __restrict__ g1, const float* __restrict__ b1,
    const float* __restrict__ g2, const float* __restrict__ b2,
    const float* __restrict__ kk,
    unsigned short* __restrict__ fuse_bf, unsigned short* __restrict__ att0_bf,
    unsigned short* __restrict__ f1_bf,
    float* __restrict__ f2_f32, unsigned short* __restrict__ f2_bf)
{
    constexpr int CI = 128;
    __shared__ unsigned short xs[128 * CI];          // 32 KB
    __shared__ unsigned short ws[4 * 192 * 32];      // 48 KB
    const int b = blockIdx.y;
    const int ty = (blockIdx.x >> 3) * 8, tx = (blockIdx.x & 7) * 16;
    const int tid = threadIdx.x;
    const int lane = tid & 63, wv = tid >> 6;
    const int n = lane & 15, quad = lane >> 4;

    {
        const uint4* gw = (const uint4*)Wp;
        uint4* lw = (uint4*)ws;
#pragma unroll
        for (int s = 0; s < 12; ++s) lw[tid + s * 256] = gw[tid + s * 256];
    }
    for (int e = tid; e < 128 * 16; e += 256) {
        int ci8 = e & 15, pxl = e >> 4;
        int gy = ty + (pxl >> 4), gx = tx + (pxl & 15);
        const unsigned short* src = (ci8 >= 8) ? Xb : Xa;
        int c8 = ci8 & 7;
        uint4 v = *(const uint4*)(src + (((size_t)b * HW + gy * 128 + gx) * 64 + c8 * 8));
        *(uint4*)(&xs[(size_t)pxl * CI + ((ci8 ^ (pxl & 7)) << 3)]) = v;
    }
    __syncthreads();

    f32x4 acc[12][2];
#pragma unroll
    for (int mb = 0; mb < 12; ++mb)
#pragma unroll
        for (int nt = 0; nt < 2; ++nt) acc[mb][nt] = (f32x4){0.f, 0.f, 0.f, 0.f};

    const int r0 = wv * 2;
#pragma unroll
    for (int ch = 0; ch < 4; ++ch) {
        bf16x8 bfr[2];
#pragma unroll
        for (int nt = 0; nt < 2; ++nt) {
            int pxl = (r0 + nt) * 16 + n;
            bfr[nt] = *(const bf16x8*)(&xs[(size_t)pxl * CI +
                                           (((ch * 4 + quad) ^ (pxl & 7)) << 3)]);
        }
#pragma unroll
        for (int mb = 0; mb < 12; ++mb) {
            bf16x8 af = *(const bf16x8*)(ws + (ch * 192 + mb * 16 + n) * 32 + quad * 8);
#pragma unroll
            for (int nt = 0; nt < 2; ++nt)
                acc[mb][nt] = __builtin_amdgcn_mfma_f32_16x16x32_bf16(
                    af, bfr[nt], acc[mb][nt], 0, 0, 0);
        }
    }

    const float rs = rsqrtf(EPSC);
#pragma unroll
    for (int mb = 0; mb < 12; ++mb) {
#pragma unroll
        for (int nt = 0; nt < 2; ++nt) {
            const int py = ty + r0 + nt;
            const int px = tx + n;
            const size_t pix = (size_t)b * HW + py * 128 + px;
            const int cg = mb * 16 + quad * 4;     // 0..191
            if (mb < 4) {
                float v4[4], s4[4];
#pragma unroll
                for (int rg = 0; rg < 4; ++rg) {
                    int co = cg + rg;
                    float base = cva[b * 64 + co] + 2.0f * cbias[co];
                    float fa = (acc[mb][nt][rg] + base) *
                               (1.0f + kse_val(kk + (size_t)(b * 64 + co) * 25, py, px));
                    v4[rg] = fa;
                    s4[rg] = 1.0f / (1.0f + __expf(-fa));
                }
                *(ushort4*)(fuse_bf + pix * 64 + cg) =
                    (ushort4){f2bf(v4[0]), f2bf(v4[1]), f2bf(v4[2]), f2bf(v4[3])};
                *(ushort4*)(att0_bf + pix * 64 + cg) =
                    (ushort4){f2bf(s4[0]), f2bf(s4[1]), f2bf(s4[2]), f2bf(s4[3])};
            } else if (mb < 8) {
                int co0 = cg - 64;
                float v4[4];
#pragma unroll
                for (int rg = 0; rg < 4; ++rg) {
                    float v = fmaf(acc[mb][nt][rg], g1[co0 + rg] * rs, b1[co0 + rg]);
                    v4[rg] = v >= 0.f ? v : 0.01f * v;
                }
                *(ushort4*)(f1_bf + pix * 64 + co0) =
                    (ushort4){f2bf(v4[0]), f2bf(v4[1]), f2bf(v4[2]), f2bf(v4[3])};
            } else {
                int co0 = cg - 128;
                float v4[4];
#pragma unroll
                for (int rg = 0; rg < 4; ++rg) {
                    float v = fmaf(acc[mb][nt][rg], g2[co0 + rg] * rs, b2[co0 + rg]);
                    v4[rg] = v >= 0.f ? v : 0.01f * v;
                    f2_f32[(size_t)(b * 64 + co0 + rg) * HW + py * 128 + px] = v4[rg];
                }
                *(ushort4*)(f2_bf + pix * 64 + co0) =
                    (ushort4){f2bf(v4[0]), f2bf(v4[1]), f2bf(v4[2]), f2bf(v4[3])};
            }
        }
    }
}

// ---------------- dyn multi-dilation depthwise 5x5 (d=1,2,3) + (1+kse); bf16 NHWC out ----------------
__global__ __launch_bounds__(256) void dyndil_kernel(const float* __restrict__ f2,
                                                     const float* __restrict__ kk,
                                                     unsigned short* __restrict__ out2bf) {
    __shared__ float xl[44][148];
    int b = blockIdx.x >> 8, c = (blockIdx.x >> 2) & 63, band = blockIdx.x & 3;
    int y0 = band * 32;
    int tid = threadIdx.x;
    int r = tid >> 3, s = tid & 7;
    int x0 = s * 16;
    int y = y0 + r;
    const float* xp = f2 + (size_t)(b * 64 + c) * HW;
    const float* kt = kk + (size_t)(b * 64 + c) * 25;
    float acc[16];

    if (b != 0) {
        for (int e = tid; e < 44 * 148; e += 256) {
            int rr = e / 148, cc = e - rr * 148;
            int yy = y0 + rr - 6, xx = cc - 8;
            float v = 0.f;
            if (yy >= 0 && yy < 128 && xx >= 0 && xx < 128)
                v = xp[yy * 128 + xx];
            xl[rr][cc] = v;
        }
        float kw[25];
#pragma unroll
        for (int i = 0; i < 25; i++) kw[i] = kt[i];
        __syncthreads();
#pragma unroll
        for (int e = 0; e < 16; e++) acc[e] = 0.f;
        int rr = r + 6;
        float win[32];
#define LOADROW(OFF) { const float4* p4 = (const float4*)&xl[rr + (OFF)][x0]; \
        float4 t0=p4[0],t1=p4[1],t2=p4[2],t3=p4[3],t4=p4[4],t5=p4[5],t6=p4[6],t7=p4[7]; \
        win[0]=t0.x;win[1]=t0.y;win[2]=t0.z;win[3]=t0.w; win[4]=t1.x;win[5]=t1.y;win[6]=t1.z;win[7]=t1.w; \
        win[8]=t2.x;win[9]=t2.y;win[10]=t2.z;win[11]=t2.w; win[12]=t3.x;win[13]=t3.y;win[14]=t3.z;win[15]=t3.w; \
        win[16]=t4.x;win[17]=t4.y;win[18]=t4.z;win[19]=t4.w; win[20]=t5.x;win[21]=t5.y;win[22]=t5.z;win[23]=t5.w; \
        win[24]=t6.x;win[25]=t6.y;win[26]=t6.z;win[27]=t6.w; win[28]=t7.x;win[29]=t7.y;win[30]=t7.z;win[31]=t7.w; }
#define APPLY(DIL, I) { \
        _Pragma("unroll") for (int j = 0; j < 5; j++) { \
            float wv = kw[(I)*5 + j]; int o = 8 + (j - 2) * (DIL); \
            _Pragma("unroll") for (int e2 = 0; e2 < 16; e2++) \
                acc[e2] = fmaf(wv, win[e2 + o], acc[e2]); } }
        LOADROW(-6) APPLY(3,0)
        LOADROW(-4) APPLY(2,0)
        LOADROW(-3) APPLY(3,1)
        LOADROW(-2) APPLY(1,0) APPLY(2,1)
        LOADROW(-1) APPLY(1,1)
        LOADROW(0)  APPLY(1,2) APPLY(2,2) APPLY(3,2)
        LOADROW(1)  APPLY(1,3)
        LOADROW(2)  APPLY(1,4) APPLY(2,3)
        LOADROW(3)  APPLY(3,3)
        LOADROW(4)  APPLY(2,4)
        LOADROW(6)  APPLY(3,4)
#undef LOADROW
#undef APPLY
    } else {
        const float4* p4 = (const float4*)(xp + y * 128 + x0);
#pragma unroll
        for (int i = 0; i < 4; i++) {
            float4 v = p4[i];
            acc[i*4] = v.x; acc[i*4+1] = v.y; acc[i*4+2] = v.z; acc[i*4+3] = v.w;
        }
    }
    float ys = y * (4.0f / 127.0f);
    int yi0 = (int)ys; if (yi0 > 4) yi0 = 4;
    int yi1 = yi0 + 1; if (yi1 > 4) yi1 = 4;
    float wy = ys - (float)yi0;
    float ry0 = kt[yi0*5+0] * (1.f-wy) + kt[yi1*5+0] * wy;
    float ry1 = kt[yi0*5+1] * (1.f-wy) + kt[yi1*5+1] * wy;
    float ry2 = kt[yi0*5+2] * (1.f-wy) + kt[yi1*5+2] * wy;
    float ry3 = kt[yi0*5+3] * (1.f-wy) + kt[yi1*5+3] * wy;
    float ry4 = kt[yi0*5+4] * (1.f-wy) + kt[yi1*5+4] * wy;
    unsigned short* op = out2bf + ((size_t)b * HW + (size_t)y * 128 + x0) * 64 + c;
#pragma unroll
    for (int e = 0; e < 16; e++) {
        int x = x0 + e;
        float xs2 = x * (4.0f / 127.0f);
        int xi0 = (int)xs2; if (xi0 > 4) xi0 = 4;
        float wx = xs2 - (float)xi0;
        float a = xi0==0 ? ry0 : xi0==1 ? ry1 : xi0==2 ? ry2 : xi0==3 ? ry3 : ry4;
        float bs = xi0>=3 ? ry4 : (xi0==2 ? ry3 : (xi0==1 ? ry2 : ry1));
        float kv = a + (bs - a) * wx;
        op[(size_t)e * 64] = f2bf(acc[e] * (1.0f + kv));
    }
}

// ---------------- final: att0 * sesc * outb * A1 (NHWC bf16 -> NCHW f32) ----------------
__global__ void final_kernel(const unsigned short* __restrict__ att0,
                             const float* __restrict__ scale,
                             const unsigned short* __restrict__ outb,
                             const unsigned short* __restrict__ a1,
                             float* __restrict__ o) {
    __shared__ float t[64][65];
    int b = blockIdx.y;
    int p0 = blockIdx.x * 64;
    int tid = threadIdx.x;
    for (int e = tid; e < 4096; e += 256) {
        int px = e >> 6, c = e & 63;
        size_t idx = ((size_t)b * HW + p0 + px) * 64 + c;
        t[c][px] = bf2f(att0[idx]) * scale[b * 64 + c] * bf2f(outb[idx]) * bf2f(a1[idx]);
    }
    __syncthreads();
    for (int e = tid; e < 4096; e += 256) {
        int c = e >> 6, px = e & 63;
        o[((size_t)b * 64 + c) * HW + p0 + px] = t[c][px];
    }
}

extern "C" void kernel_launch(void* const* d_in, const int* in_sizes, int n_in,
                              void* d_out, int out_size, void* d_ws, size_t ws_size,
                              hipStream_t stream) {
    const float* x1      = (const float*)d_in[0];
    const float* kk      = (const float*)d_in[1];
    const float* conv1_w = (const float*)d_in[2];
    const float* conv1_g = (const float*)d_in[3];
    const float* conv1_b = (const float*)d_in[4];
    const float* conv2_w = (const float*)d_in[5];
    const float* conv2_g = (const float*)d_in[6];
    const float* conv2_b = (const float*)d_in[7];
    const float* conv_w  = (const float*)d_in[8];
    const float* conv_bias = (const float*)d_in[9];
    const float* c0_w  = (const float*)d_in[10];
    const float* c0_g  = (const float*)d_in[11];
    const float* c0_b  = (const float*)d_in[12];
    const float* attc_w = (const float*)d_in[13];
    const float* attc_g = (const float*)d_in[14];
    const float* attc_b = (const float*)d_in[15];
    const float* c05_w = (const float*)d_in[16];
    const float* c05_g = (const float*)d_in[17];
    const float* c05_b = (const float*)d_in[18];
    const float* conv0a_w = (const float*)d_in[19];
    const float* conv0a_g = (const float*)d_in[20];
    const float* conv0a_b = (const float*)d_in[21];
    const float* conv0b_w = (const float*)d_in[22];
    const float* conv0b_g = (const float*)d_in[23];
    const float* conv0b_b = (const float*)d_in[24];
    const float* se_w1 = (const float*)d_in[25];
    const float* se_w2 = (const float*)d_in[26];

    // ---- workspace: 16 MB units, aggressive aliasing by liveness ----
    const size_t U = (size_t)8 * HW * 64 * 2;           // 16,777,216 B
    unsigned char* P = (unsigned char*)d_ws;
    unsigned short* x1a        = (unsigned short*)(P + 0 * U);
    unsigned short* x1b        = (unsigned short*)(P + 1 * U);
    unsigned short* att0_bf    = (unsigned short*)(P + 2 * U);
    unsigned short* fuse_bf    = (unsigned short*)(P + 3 * U);
    unsigned short* f1_bf      = (unsigned short*)(P + 4 * U);
    float*          f2         = (float*)         (P + 5 * U);   // 2 units, f32 NCHW (dyndil)
    unsigned short* f2_bf      = (unsigned short*)(P + 7 * U);
    unsigned short* A1_bf      = (unsigned short*)(P + 8 * U);
    unsigned short* eadd_bf    = (unsigned short*)(P + 9 * U);
    unsigned short* out1_bf    = (unsigned short*)(P + 10 * U);
    unsigned short* A12_bf     = (unsigned short*)(P + 11 * U);
    // aliases (dead ranges reused)
    unsigned short* out2_bf     = x1a;      // after 1x1s
    unsigned short* oc_bf       = x1b;      // after 1x1s
    unsigned short* fuseout2_bf = fuse_bf;  // after 3x3#1
    unsigned short* eout2_bf    = f1_bf;    // after 3x3#3
    unsigned short* out2fin_bf  = eadd_bf;  // after 3x3#2
    unsigned short* outb_bf     = out1_bf;  // after conv0a
    unsigned short* outa_bf     = A12_bf;   // after 5x5#1

    unsigned char* W0 = P + 12 * U;
    unsigned short* Wp1   = (unsigned short*)(W0);             // 49152
    unsigned short* Wc0   = (unsigned short*)(W0 + 49152);     // 73728
    unsigned short* Wattc = (unsigned short*)(W0 + 122880);    // 73728
    unsigned short* Wc05  = (unsigned short*)(W0 + 196608);    // 204800
    unsigned short* Wc0a  = (unsigned short*)(W0 + 401408);    // 16384
    unsigned short* Wc0b  = (unsigned short*)(W0 + 417792);    // 73728
    float* va   = (float*)(W0 + 491520);   // 1024
    float* cva  = va + 1024;               // 512
    float* part = cva + 512;               // 8*16*64
    float* sesc = part + 8192;             // 512

    const dim3 g32(64, 8);     // 32x32 convs: 8x8 tiles of 16x16 px
    const dim3 g16(128, 8);    // 16x16 convs: 16x8 tiles of 8x16 px

    // ---- prep ----
    mean_hw_kernel<<<1024, 256, 0, stream>>>(x1, va);
    convva_kernel<<<1, 512, 0, stream>>>(va, conv_w, cva);
    repack_x1_kernel<<<dim3(256, 8), 256, 0, stream>>>(x1, x1a, x1b);
    prep_w_kernel<<<32, 256, 0, stream>>>(conv_w,   Wp1, 64, 128, 1, 192, 0);
    prep_w_kernel<<<32, 256, 0, stream>>>(conv1_w,  Wp1, 64, 128, 1, 192, 64);
    prep_w_kernel<<<32, 256, 0, stream>>>(conv2_w,  Wp1, 64, 128, 1, 192, 128);
    prep_w32_kernel<<<144, 256, 0, stream>>>(c0_w,    Wc0,   64, 64, 3);
    prep_w32_kernel<<<144, 256, 0, stream>>>(attc_w,  Wattc, 64, 64, 3);
    prep_w32_kernel<<<400, 256, 0, stream>>>(c05_w,   Wc05,  64, 64, 5);
    prep_w16_kernel<<<32, 256, 0, stream>>>(conv0a_w, Wc0a,  64, 128);
    prep_w32_kernel<<<144, 256, 0, stream>>>(conv0b_w, Wc0b, 64, 64, 3);

    // ---- merged 1x1 triple over x1 ----
    conv1x1_triple<<<g16, 256, 0, stream>>>(x1a, x1b, Wp1, cva, conv_bias,
        conv1_g, conv1_b, conv2_g, conv2_b, kk, fuse_bf, att0_bf, f1_bf, f2, f2_bf);

    att_mean_part<<<dim3(16, 8), 256, 0, stream>>>(att0_bf, part);
    se_mlp_kernel<<<1, 512, 0, stream>>>(part, se_w1, se_w2, sesc);

    // ---- dyndil (reads f2 f32 NCHW, writes bf16 NHWC; overwrites x1a) ----
    dyndil_kernel<<<2048, 256, 0, stream>>>(f2, kk, out2_bf);

    // ---- 3x3 chain ----
    conv_mfma32<3><<<g32, 256, 0, stream>>>(fuse_bf, Wc0,
        c0_g, c0_b, kk, nullptr, nullptr, eadd_bf, nullptr, 0);
    conv_mfma32<3><<<g32, 256, 0, stream>>>(eadd_bf, Wattc,
        attc_g, attc_b, kk, nullptr, nullptr, A1_bf, nullptr, 1);
    conv_mfma32<3><<<g32, 256, 0, stream>>>(f1_bf, Wc0,
        c0_g, c0_b, kk, nullptr, nullptr, out1_bf, nullptr, 2);
    conv_mfma32<3><<<g32, 256, 0, stream>>>(out1_bf, Wattc,
        attc_g, attc_b, kk, A1_bf, nullptr, A12_bf, nullptr, 6);

    // ---- 5x5 chain (elementwise fused into epilogues) ----
    conv_mfma32<5><<<g32, 256, 0, stream>>>(out2_bf, Wc05,
        c05_g, c05_b, kk, A12_bf, nullptr, oc_bf, fuseout2_bf, 4);
    conv_mfma32<5><<<g32, 256, 0, stream>>>(fuseout2_bf, Wc05,
        c05_g, c05_b, kk, oc_bf, f2_bf, eout2_bf, nullptr, 5);
    conv_mfma32<5><<<g32, 256, 0, stream>>>(eout2_bf, Wc05,
        c05_g, c05_b, kk, nullptr, nullptr, out2fin_bf, nullptr, 0);

    // ---- head ----
    conv_mfma1x1<<<g16, 256, 0, stream>>>(out1_bf, out2fin_bf, Wc0a,
        conv0a_g, conv0a_b, outa_bf);
    conv_mfma32<3><<<g32, 256, 0, stream>>>(outa_bf, Wc0b,
        conv0b_g, conv0b_b, kk, nullptr, nullptr, outb_bf, nullptr, 0);
    final_kernel<<<dim3(256, 8), 256, 0, stream>>>(att0_bf, sesc, outb_bf, A1_bf, (float*)d_out);
}

// Round 8
// 577.331 us; speedup vs baseline: 1.1738x; 1.1738x over previous
//
#include <hip/hip_runtime.h>
#include <math.h>

#define HW 16384
#define EPSC 1.00001f   // 1 + 1e-5

typedef short bf16x8 __attribute__((ext_vector_type(8)));
typedef float f32x4 __attribute__((ext_vector_type(4)));

static __device__ __forceinline__ unsigned short f2bf(float f) {
    unsigned int u = __float_as_uint(f);
    unsigned int r = (u + 0x7fffu + ((u >> 16) & 1u)) >> 16;
    return (unsigned short)r;
}
static __device__ __forceinline__ float bf2f(unsigned short u) {
    return __uint_as_float(((unsigned int)u) << 16);
}

union U16B { uint4 v; unsigned short s[8]; };

// ---------------- mean over H*W (per (b,c) plane, f32 NCHW) ----------------
__global__ void mean_hw_kernel(const float* __restrict__ x, float* __restrict__ out) {
    int blk = blockIdx.x;
    const float4* p4 = (const float4*)(x + (size_t)blk * HW);
    float s = 0.f;
    for (int i = threadIdx.x; i < HW / 4; i += 256) {
        float4 v = p4[i];
        s += v.x + v.y + v.z + v.w;
    }
    for (int off = 32; off > 0; off >>= 1) s += __shfl_down(s, off, 64);
    __shared__ float red[4];
    int lane = threadIdx.x & 63, wid = threadIdx.x >> 6;
    if (lane == 0) red[wid] = s;
    __syncthreads();
    if (threadIdx.x == 0)
        out[blk] = (red[0] + red[1] + red[2] + red[3]) * (1.0f / (float)HW);
}

__global__ void convva_kernel(const float* __restrict__ va, const float* __restrict__ cw,
                              float* __restrict__ out) {
    int t = threadIdx.x;           // 512 = 8*64
    int b = t >> 6, co = t & 63;
    float s = 0.f;
    for (int ci = 0; ci < 128; ci++) s = fmaf(cw[co * 128 + ci], va[b * 128 + ci], s);
    out[t] = s;
}

// ---------------- partial mean of att0 (bf16 NHWC) ----------------
__global__ void att_mean_part(const unsigned short* __restrict__ att0, float* __restrict__ part) {
    int s = blockIdx.x, b = blockIdx.y;
    int c = threadIdx.x & 63, pr = threadIdx.x >> 6;
    const unsigned short* p = att0 + ((size_t)b * HW + s * 1024 + pr * 256) * 64 + c;
    float acc = 0.f;
    for (int i = 0; i < 256; i++) acc += bf2f(p[(size_t)i * 64]);
    __shared__ float red[4][64];
    red[pr][c] = acc;
    __syncthreads();
    if (threadIdx.x < 64)
        part[(b * 16 + s) * 64 + threadIdx.x] =
            red[0][threadIdx.x] + red[1][threadIdx.x] + red[2][threadIdx.x] + red[3][threadIdx.x];
}

__global__ void se_mlp_kernel(const float* __restrict__ part, const float* __restrict__ w1,
                              const float* __restrict__ w2, float* __restrict__ scale) {
    __shared__ float t[8][4];
    __shared__ float ym[8][64];
    int tid = threadIdx.x;         // 512
    {
        int b = tid >> 6, c = tid & 63;
        float s = 0.f;
        for (int i = 0; i < 16; i++) s += part[(b * 16 + i) * 64 + c];
        ym[b][c] = s * (1.0f / (float)HW);
    }
    __syncthreads();
    if (tid < 32) {
        int b = tid >> 2, h = tid & 3;
        float s = 0.f;
        for (int ci = 0; ci < 64; ci++) s = fmaf(ym[b][ci], w1[h * 64 + ci], s);
        t[b][h] = s >= 0.f ? s : 0.01f * s;
    }
    __syncthreads();
    int b = tid >> 6, c = tid & 63;
    float s = 0.f;
    for (int h = 0; h < 4; h++) s = fmaf(t[b][h], w2[c * 4 + h], s);
    scale[b * 64 + c] = 1.0f / (1.0f + __expf(-s));
}

// kse bilinear (align-corners): k table is 25 floats for (b,c)
__device__ __forceinline__ float kse_val(const float* kt, int y, int x) {
    float ys = y * (4.0f / 127.0f);
    int y0 = (int)ys; if (y0 > 4) y0 = 4;
    int y1 = min(y0 + 1, 4);
    float wy = ys - (float)y0;
    float xs = x * (4.0f / 127.0f);
    int x0 = (int)xs; if (x0 > 4) x0 = 4;
    int x1 = min(x0 + 1, 4);
    float wx = xs - (float)x0;
    float r0 = kt[y0 * 5 + x0] * (1.f - wx) + kt[y0 * 5 + x1] * wx;
    float r1 = kt[y1 * 5 + x0] * (1.f - wx) + kt[y1 * 5 + x1] * wx;
    return r0 * (1.f - wy) + r1 * wy;
}

// ---------------- repack x1 f32 NCHW[128][HW] -> two bf16 NHWC [HW][64] ----------------
__global__ void repack_x1_kernel(const float* __restrict__ x1,
                                 unsigned short* __restrict__ xa,
                                 unsigned short* __restrict__ xb) {
    __shared__ float t[64][65];
    int b = blockIdx.y;
    int p0 = blockIdx.x * 64;
    for (int h = 0; h < 2; ++h) {
        const float* src = x1 + ((size_t)b * 128 + h * 64) * HW + p0;
        __syncthreads();
        for (int e = threadIdx.x; e < 4096; e += 256) {
            int ci = e >> 6, px = e & 63;
            t[ci][px] = src[(size_t)ci * HW + px];
        }
        __syncthreads();
        unsigned short* dst = (h == 0 ? xa : xb) + ((size_t)b * HW + p0) * 64;
        for (int e = threadIdx.x; e < 4096; e += 256) {
            int px = e >> 6, ci = e & 63;
            dst[(size_t)px * 64 + ci] = f2bf(t[ci][px]);
        }
    }
}

// ---------------- repack f32 NCHW[64][HW] -> bf16 NHWC [HW][64] ----------------
__global__ void repack64_kernel(const float* __restrict__ src, unsigned short* __restrict__ dst) {
    __shared__ float t[64][65];
    int b = blockIdx.y;
    int p0 = blockIdx.x * 64;
    for (int e = threadIdx.x; e < 4096; e += 256) {
        int ci = e >> 6, px = e & 63;
        t[ci][px] = src[((size_t)b * 64 + ci) * HW + p0 + px];
    }
    __syncthreads();
    for (int e = threadIdx.x; e < 4096; e += 256) {
        int px = e >> 6, ci = e & 63;
        dst[((size_t)b * HW + p0 + px) * 64 + ci] = f2bf(t[ci][px]);
    }
}

// ---------------- W pack for 1x1 triple (CI=128, co_total=192): [ch][mb12][lane][8] ----------------
__global__ void prep_w1x1_kernel(const float* __restrict__ src, unsigned short* __restrict__ dst,
                                 int co_off) {
    int idx = blockIdx.x * 256 + threadIdx.x;
    if (idx >= 64 * 128) return;
    int ci = idx % 128, co = idx / 128;
    int ch = ci >> 5, q = (ci >> 3) & 3, j = ci & 7;
    int gco = co_off + co;
    int mb = gco >> 4, lane = q * 16 + (gco & 15);
    dst[(((size_t)ch * 12 + mb) * 64 + lane) * 8 + j] = f2bf(src[idx]);
}

// ---------------- W pack for tap-relayed conv (CI=64): [tap][chunk2][mb4][lane][8] ----------------
__global__ void prep_wtap_kernel(const float* __restrict__ src, unsigned short* __restrict__ dst,
                                 int K) {
    int idx = blockIdx.x * 256 + threadIdx.x;
    int total = 64 * 64 * K * K;
    if (idx >= total) return;
    int kx = idx % K, t1 = idx / K;
    int ky = t1 % K, t2 = t1 / K;
    int ci = t2 % 64, co = t2 / 64;
    int tap = ky * K + kx;
    int chunk = ci >> 5, q = (ci >> 3) & 3, j = ci & 7;
    int lane = q * 16 + (co & 15), mb = (co >> 4) & 3;
    dst[((((size_t)tap * 2 + chunk) * 4 + mb) * 64 + lane) * 8 + j] = f2bf(src[idx]);
}

// ---------------- W pack for conv0a (CI=128 -> 64co): [ch4][mb4][lane][8] ----------------
__global__ void prep_w16_kernel(const float* __restrict__ src, unsigned short* __restrict__ dst) {
    int idx = blockIdx.x * 256 + threadIdx.x;
    if (idx >= 64 * 128) return;
    int ci = idx % 128, co = idx / 128;
    int ch = ci >> 5, q = (ci >> 3) & 3, j = ci & 7;
    int l = q * 16 + (co & 15), mb = co >> 4;
    dst[(((size_t)ch * 4 + mb) * 64 + l) * 8 + j] = f2bf(src[idx]);
}

// ---------------- MFMA implicit conv (CI=64): W LDS-relayed per tap, dense epilogue ----------------
// Block: 64 co x (8 x 16) px.  emode: 0=bnlrelu  1=sigmoid(bnlrelu)  2=bnlrelu*(1+kse)
//   4=bnlrelu->out_bf; aux_bf=eB*v   5=bnlrelu+eB+eC->out_bf   6=sigmoid(bnlrelu)*eB->out_bf
template<int KSZ>
__global__ __launch_bounds__(256, 3) void conv_mfma(
    const unsigned short* __restrict__ Xa,
    const unsigned short* __restrict__ Wp,
    const float* __restrict__ g, const float* __restrict__ bb,
    const float* __restrict__ kk,
    const unsigned short* __restrict__ eB, const unsigned short* __restrict__ eC,
    unsigned short* __restrict__ out_bf, unsigned short* __restrict__ aux_bf, int emode)
{
    constexpr int PAD = KSZ / 2;
    constexpr int TWX = 16 + 2 * PAD;
    constexpr int TWY = 8 + 2 * PAD;
    constexpr int NTAP = KSZ * KSZ;
    constexpr int WSLAB = 4096;                  // shorts per tap slab (8 KB)
    __shared__ unsigned short xs[TWY * TWX * 64];
    __shared__ unsigned short ws[2 * WSLAB];

    const int b = blockIdx.y;
    const int ty = (blockIdx.x >> 3) * 8, tx = (blockIdx.x & 7) * 16;
    const int tid = threadIdx.x;
    const int lane = tid & 63, wv = tid >> 6;
    const int n = lane & 15, quad = lane >> 4;

    // ---- prefetch W tap 0 ----
    uint4 wst[2];
    {
        const uint4* gw = (const uint4*)Wp;
#pragma unroll
        for (int s = 0; s < 2; ++s) wst[s] = gw[tid + s * 256];
    }
    // ---- stage X tile (swizzled 8-short groups) ----
    for (int e = tid; e < TWY * TWX * 8; e += 256) {
        int ci8 = e & 7, pxl = e >> 3;
        int xx = pxl % TWX, yy = pxl / TWX;
        int gy = ty + yy - PAD, gx = tx + xx - PAD;
        uint4 v = {0u, 0u, 0u, 0u};
        if (gy >= 0 && gy < 128 && gx >= 0 && gx < 128)
            v = *(const uint4*)(Xa + (((size_t)b * HW + gy * 128 + gx) * 64 + ci8 * 8));
        *(uint4*)(&xs[(size_t)pxl * 64 + ((ci8 ^ (pxl & 7)) << 3)]) = v;
    }
    {
        uint4* lw = (uint4*)ws;
#pragma unroll
        for (int s = 0; s < 2; ++s) lw[tid + s * 256] = wst[s];
    }
    __syncthreads();

    f32x4 acc[4][2];
#pragma unroll
    for (int mb = 0; mb < 4; ++mb)
#pragma unroll
        for (int nt = 0; nt < 2; ++nt) acc[mb][nt] = (f32x4){0.f, 0.f, 0.f, 0.f};

    const int r0 = wv * 2;
    for (int tap = 0; tap < NTAP; ++tap) {
        if (tap + 1 < NTAP) {
            const uint4* gw = (const uint4*)Wp + (size_t)(tap + 1) * (WSLAB / 8);
#pragma unroll
            for (int s = 0; s < 2; ++s) wst[s] = gw[tid + s * 256];
        }
        const unsigned short* wl = ws + (tap & 1) * WSLAB;
        const int ky = tap / KSZ, kx = tap - ky * KSZ;
#pragma unroll
        for (int ch = 0; ch < 2; ++ch) {
            bf16x8 af[4];
#pragma unroll
            for (int mb = 0; mb < 4; ++mb)
                af[mb] = *(const bf16x8*)(wl + ((ch * 4 + mb) * 64 + lane) * 8);
            bf16x8 bfr[2];
#pragma unroll
            for (int nt = 0; nt < 2; ++nt) {
                int pxl = (r0 + nt + ky) * TWX + n + kx;
                bfr[nt] = *(const bf16x8*)(&xs[(size_t)pxl * 64 +
                                               (((ch * 4 + quad) ^ (pxl & 7)) << 3)]);
            }
#pragma unroll
            for (int mb = 0; mb < 4; ++mb)
#pragma unroll
                for (int nt = 0; nt < 2; ++nt)
                    acc[mb][nt] = __builtin_amdgcn_mfma_f32_16x16x32_bf16(
                        af[mb], bfr[nt], acc[mb][nt], 0, 0, 0);
        }
        if (tap + 1 < NTAP) {
            uint4* lw = (uint4*)(ws + ((tap + 1) & 1) * WSLAB);
#pragma unroll
            for (int s = 0; s < 2; ++s) lw[tid + s * 256] = wst[s];
            __syncthreads();
        }
    }

    // ---- dense epilogue: stage bf16 results in xs (swizzled), then coalesced stores ----
    __syncthreads();                 // all waves done reading xs/ws
    unsigned short* stg = xs;
    const float rs = rsqrtf(EPSC);
#pragma unroll
    for (int mb = 0; mb < 4; ++mb) {
#pragma unroll
        for (int nt = 0; nt < 2; ++nt) {
            const int pixl = (r0 + nt) * 16 + n;
            const int py = ty + r0 + nt, px = tx + n;
            const int co0 = mb * 16 + quad * 4;
            float v4[4];
#pragma unroll
            for (int rg = 0; rg < 4; ++rg) {
                int co = co0 + rg;
                float v = fmaf(acc[mb][nt][rg], g[co] * rs, bb[co]);
                v = v >= 0.f ? v : 0.01f * v;
                if (emode == 1 || emode == 6) v = 1.0f / (1.0f + __expf(-v));
                else if (emode == 2)
                    v *= (1.0f + kse_val(kk + (size_t)(b * 64 + co) * 25, py, px));
                v4[rg] = v;
            }
            int gq = co0 >> 3, rem = co0 & 7;
            *(ushort4*)(stg + pixl * 64 + ((gq ^ (pixl & 7)) << 3) + rem) =
                (ushort4){f2bf(v4[0]), f2bf(v4[1]), f2bf(v4[2]), f2bf(v4[3])};
        }
    }
    __syncthreads();
#pragma unroll
    for (int it = 0; it < 4; ++it) {
        int idx = it * 256 + tid;
        int pixl = idx >> 3, s = idx & 7;
        int cog = s ^ (pixl & 7);
        U16B v; v.v = *(const uint4*)(stg + pixl * 64 + s * 8);
        int py = ty + (pixl >> 4), px = tx + (pixl & 15);
        size_t gofs = ((size_t)b * HW + py * 128 + px) * 64 + cog * 8;
        if (emode == 6) {
            U16B e; e.v = *(const uint4*)(eB + gofs);
            U16B o;
#pragma unroll
            for (int j = 0; j < 8; ++j) o.s[j] = f2bf(bf2f(v.s[j]) * bf2f(e.s[j]));
            *(uint4*)(out_bf + gofs) = o.v;
        } else if (emode == 4) {
            *(uint4*)(out_bf + gofs) = v.v;
            U16B e; e.v = *(const uint4*)(eB + gofs);
            U16B o;
#pragma unroll
            for (int j = 0; j < 8; ++j) o.s[j] = f2bf(bf2f(v.s[j]) * bf2f(e.s[j]));
            *(uint4*)(aux_bf + gofs) = o.v;
        } else if (emode == 5) {
            U16B e1; e1.v = *(const uint4*)(eB + gofs);
            U16B e2; e2.v = *(const uint4*)(eC + gofs);
            U16B o;
#pragma unroll
            for (int j = 0; j < 8; ++j)
                o.s[j] = f2bf(bf2f(v.s[j]) + bf2f(e1.s[j]) + bf2f(e2.s[j]));
            *(uint4*)(out_bf + gofs) = o.v;
        } else {
            *(uint4*)(out_bf + gofs) = v.v;
        }
    }
}

// ---------------- merged 1x1 triple over x1 (CI=128 -> 192co), dense epilogue ----------------
__global__ __launch_bounds__(256, 2) void conv1x1_triple(
    const unsigned short* __restrict__ Xa, const unsigned short* __restrict__ Xb,
    const unsigned short* __restrict__ Wp,
    const float* __restrict__ cva, const float* __restrict__ cbias,
    const float* __restrict__ g1, const float* __restrict__ b1,
    const float* __restrict__ g2, const float* __restrict__ b2,
    const float* __restrict__ kk,
    unsigned short* __restrict__ fuse_bf, unsigned short* __restrict__ att0_bf,
    unsigned short* __restrict__ f1_bf,
    float* __restrict__ f2_f32, unsigned short* __restrict__ f2_bf)
{
    constexpr int CI = 128;
    __shared__ unsigned short xs[128 * CI];          // 32 KB
    __shared__ unsigned short ws[4 * 12 * 64 * 8];   // 48 KB
    const int b = blockIdx.y;
    const int ty = (blockIdx.x >> 3) * 8, tx = (blockIdx.x & 7) * 16;
    const int tid = threadIdx.x;
    const int lane = tid & 63, wv = tid >> 6;
    const int n = lane & 15, quad = lane >> 4;

    {
        const uint4* gw = (const uint4*)Wp;
        uint4* lw = (uint4*)ws;
#pragma unroll
        for (int s = 0; s < 12; ++s) lw[tid + s * 256] = gw[tid + s * 256];
    }
    for (int e = tid; e < 128 * 16; e += 256) {
        int ci8 = e & 15, pxl = e >> 4;
        int gy = ty + (pxl >> 4), gx = tx + (pxl & 15);
        const unsigned short* src = (ci8 >= 8) ? Xb : Xa;
        int c8 = ci8 & 7;
        uint4 v = *(const uint4*)(src + (((size_t)b * HW + gy * 128 + gx) * 64 + c8 * 8));
        *(uint4*)(&xs[(size_t)pxl * CI + ((ci8 ^ (pxl & 7)) << 3)]) = v;
    }
    __syncthreads();

    f32x4 acc[12][2];
#pragma unroll
    for (int mb = 0; mb < 12; ++mb)
#pragma unroll
        for (int nt = 0; nt < 2; ++nt) acc[mb][nt] = (f32x4){0.f, 0.f, 0.f, 0.f};

    const int r0 = wv * 2;
#pragma unroll
    for (int ch = 0; ch < 4; ++ch) {
        bf16x8 bfr[2];
#pragma unroll
        for (int nt = 0; nt < 2; ++nt) {
            int pxl = (r0 + nt) * 16 + n;
            bfr[nt] = *(const bf16x8*)(&xs[(size_t)pxl * CI +
                                           (((ch * 4 + quad) ^ (pxl & 7)) << 3)]);
        }
#pragma unroll
        for (int mb = 0; mb < 12; ++mb) {
            bf16x8 af = *(const bf16x8*)(ws + ((ch * 12 + mb) * 64 + lane) * 8);
#pragma unroll
            for (int nt = 0; nt < 2; ++nt)
                acc[mb][nt] = __builtin_amdgcn_mfma_f32_16x16x32_bf16(
                    af, bfr[nt], acc[mb][nt], 0, 0, 0);
        }
    }

    // ---- stage: fuse -> ws[0], f1 -> ws[8192], f2 -> xs ----
    __syncthreads();
    const float rs = rsqrtf(EPSC);
#pragma unroll
    for (int mb = 0; mb < 12; ++mb) {
#pragma unroll
        for (int nt = 0; nt < 2; ++nt) {
            const int pixl = (r0 + nt) * 16 + n;
            const int py = ty + r0 + nt, px = tx + n;
            const int t3 = mb >> 2;                 // tensor 0/1/2
            const int co0 = (mb & 3) * 16 + quad * 4;
            float v4[4];
#pragma unroll
            for (int rg = 0; rg < 4; ++rg) {
                int co = co0 + rg;
                float v;
                if (t3 == 0) {
                    float base = cva[b * 64 + co] + 2.0f * cbias[co];
                    v = (acc[mb][nt][rg] + base) *
                        (1.0f + kse_val(kk + (size_t)(b * 64 + co) * 25, py, px));
                } else if (t3 == 1) {
                    v = fmaf(acc[mb][nt][rg], g1[co] * rs, b1[co]);
                    v = v >= 0.f ? v : 0.01f * v;
                } else {
                    v = fmaf(acc[mb][nt][rg], g2[co] * rs, b2[co]);
                    v = v >= 0.f ? v : 0.01f * v;
                    f2_f32[(size_t)(b * 64 + co) * HW + py * 128 + px] = v;
                }
                v4[rg] = v;
            }
            unsigned short* stg = (t3 == 2) ? xs : (ws + t3 * 8192);
            int gq = co0 >> 3, rem = co0 & 7;
            *(ushort4*)(stg + pixl * 64 + ((gq ^ (pixl & 7)) << 3) + rem) =
                (ushort4){f2bf(v4[0]), f2bf(v4[1]), f2bf(v4[2]), f2bf(v4[3])};
        }
    }
    __syncthreads();
#pragma unroll
    for (int it = 0; it < 12; ++it) {
        int t3 = it >> 2;
        int idx = (it & 3) * 256 + tid;
        int pixl = idx >> 3, s = idx & 7;
        int cog = s ^ (pixl & 7);
        const unsigned short* stg = (t3 == 2) ? xs : (ws + t3 * 8192);
        U16B v; v.v = *(const uint4*)(stg + pixl * 64 + s * 8);
        int py = ty + (pixl >> 4), px = tx + (pixl & 15);
        size_t gofs = ((size_t)b * HW + py * 128 + px) * 64 + cog * 8;
        if (t3 == 0) {
            *(uint4*)(fuse_bf + gofs) = v.v;
            U16B o;
#pragma unroll
            for (int j = 0; j < 8; ++j)
                o.s[j] = f2bf(1.0f / (1.0f + __expf(-bf2f(v.s[j]))));
            *(uint4*)(att0_bf + gofs) = o.v;
        } else if (t3 == 1) {
            *(uint4*)(f1_bf + gofs) = v.v;
        } else {
            *(uint4*)(f2_bf + gofs) = v.v;
        }
    }
}

// ---------------- conv0a 1x1 over concat (CI=128 -> 64co), bnlrelu, dense epilogue ----------------
__global__ __launch_bounds__(256, 3) void conv_mfma1x1(
    const unsigned short* __restrict__ Xa, const unsigned short* __restrict__ Xb,
    const unsigned short* __restrict__ Wp,
    const float* __restrict__ g, const float* __restrict__ bb,
    unsigned short* __restrict__ out_bf)
{
    constexpr int CI = 128;
    __shared__ unsigned short xs[128 * CI];       // 32 KB
    __shared__ unsigned short ws[4 * 4 * 64 * 8]; // 16 KB
    const int b = blockIdx.y;
    const int ty = (blockIdx.x >> 3) * 8, tx = (blockIdx.x & 7) * 16;
    const int tid = threadIdx.x;
    const int lane = tid & 63, wv = tid >> 6;
    const int n = lane & 15, quad = lane >> 4;

    {
        const uint4* gw = (const uint4*)Wp;
        uint4* lw = (uint4*)ws;
#pragma unroll
        for (int s = 0; s < 4; ++s) lw[tid + s * 256] = gw[tid + s * 256];
    }
    for (int e = tid; e < 128 * 16; e += 256) {
        int ci8 = e & 15, pxl = e >> 4;
        int gy = ty + (pxl >> 4), gx = tx + (pxl & 15);
        const unsigned short* src = (ci8 >= 8) ? Xb : Xa;
        int c8 = ci8 & 7;
        uint4 v = *(const uint4*)(src + (((size_t)b * HW + gy * 128 + gx) * 64 + c8 * 8));
        *(uint4*)(&xs[(size_t)pxl * CI + ((ci8 ^ (pxl & 7)) << 3)]) = v;
    }
    __syncthreads();

    f32x4 acc[4][2];
#pragma unroll
    for (int mb = 0; mb < 4; ++mb)
#pragma unroll
        for (int nt = 0; nt < 2; ++nt) acc[mb][nt] = (f32x4){0.f, 0.f, 0.f, 0.f};

    const int r0 = wv * 2;
#pragma unroll
    for (int ch = 0; ch < 4; ++ch) {
        bf16x8 bfr[2];
#pragma unroll
        for (int nt = 0; nt < 2; ++nt) {
            int pxl = (r0 + nt) * 16 + n;
            bfr[nt] = *(const bf16x8*)(&xs[(size_t)pxl * CI +
                                           (((ch * 4 + quad) ^ (pxl & 7)) << 3)]);
        }
#pragma unroll
        for (int mb = 0; mb < 4; ++mb) {
            bf16x8 af = *(const bf16x8*)(ws + ((ch * 4 + mb) * 64 + lane) * 8);
#pragma unroll
            for (int nt = 0; nt < 2; ++nt)
                acc[mb][nt] = __builtin_amdgcn_mfma_f32_16x16x32_bf16(
                    af, bfr[nt], acc[mb][nt], 0, 0, 0);
        }
    }

    __syncthreads();
    const float rs = rsqrtf(EPSC);
#pragma unroll
    for (int mb = 0; mb < 4; ++mb) {
#pragma unroll
        for (int nt = 0; nt < 2; ++nt) {
            const int pixl = (r0 + nt) * 16 + n;
            const int co0 = mb * 16 + quad * 4;
            float v4[4];
#pragma unroll
            for (int rg = 0; rg < 4; ++rg) {
                float v = fmaf(acc[mb][nt][rg], g[co0 + rg] * rs, bb[co0 + rg]);
                v4[rg] = v >= 0.f ? v : 0.01f * v;
            }
            int gq = co0 >> 3, rem = co0 & 7;
            *(ushort4*)(ws + pixl * 64 + ((gq ^ (pixl & 7)) << 3) + rem) =
                (ushort4){f2bf(v4[0]), f2bf(v4[1]), f2bf(v4[2]), f2bf(v4[3])};
        }
    }
    __syncthreads();
#pragma unroll
    for (int it = 0; it < 4; ++it) {
        int idx = it * 256 + tid;
        int pixl = idx >> 3, s = idx & 7;
        int cog = s ^ (pixl & 7);
        uint4 v = *(const uint4*)(ws + pixl * 64 + s * 8);
        int py = ty + (pixl >> 4), px = tx + (pixl & 15);
        *(uint4*)(out_bf + ((size_t)b * HW + py * 128 + px) * 64 + cog * 8) = v;
    }
}

// ---------------- dyn multi-dilation depthwise 5x5 (d=1,2,3) + (1+kse); f32 NCHW out ----------------
__global__ __launch_bounds__(256) void dyndil_kernel(const float* __restrict__ f2,
                                                     const float* __restrict__ kk,
                                                     float* __restrict__ out2f) {
    __shared__ float xl[44][148];
    int b = blockIdx.x >> 8, c = (blockIdx.x >> 2) & 63, band = blockIdx.x & 3;
    int y0 = band * 32;
    int tid = threadIdx.x;
    int r = tid >> 3, s = tid & 7;
    int x0 = s * 16;
    int y = y0 + r;
    const float* xp = f2 + (size_t)(b * 64 + c) * HW;
    const float* kt = kk + (size_t)(b * 64 + c) * 25;
    float acc[16];

    if (b != 0) {
        for (int e = tid; e < 44 * 148; e += 256) {
            int rr = e / 148, cc = e - rr * 148;
            int yy = y0 + rr - 6, xx = cc - 8;
            float v = 0.f;
            if (yy >= 0 && yy < 128 && xx >= 0 && xx < 128)
                v = xp[yy * 128 + xx];
            xl[rr][cc] = v;
        }
        float kw[25];
#pragma unroll
        for (int i = 0; i < 25; i++) kw[i] = kt[i];
        __syncthreads();
#pragma unroll
        for (int e = 0; e < 16; e++) acc[e] = 0.f;
        int rr = r + 6;
        float win[32];
#define LOADROW(OFF) { const float4* p4 = (const float4*)&xl[rr + (OFF)][x0]; \
        float4 t0=p4[0],t1=p4[1],t2=p4[2],t3=p4[3],t4=p4[4],t5=p4[5],t6=p4[6],t7=p4[7]; \
        win[0]=t0.x;win[1]=t0.y;win[2]=t0.z;win[3]=t0.w; win[4]=t1.x;win[5]=t1.y;win[6]=t1.z;win[7]=t1.w; \
        win[8]=t2.x;win[9]=t2.y;win[10]=t2.z;win[11]=t2.w; win[12]=t3.x;win[13]=t3.y;win[14]=t3.z;win[15]=t3.w; \
        win[16]=t4.x;win[17]=t4.y;win[18]=t4.z;win[19]=t4.w; win[20]=t5.x;win[21]=t5.y;win[22]=t5.z;win[23]=t5.w; \
        win[24]=t6.x;win[25]=t6.y;win[26]=t6.z;win[27]=t6.w; win[28]=t7.x;win[29]=t7.y;win[30]=t7.z;win[31]=t7.w; }
#define APPLY(DIL, I) { \
        _Pragma("unroll") for (int j = 0; j < 5; j++) { \
            float wv = kw[(I)*5 + j]; int o = 8 + (j - 2) * (DIL); \
            _Pragma("unroll") for (int e2 = 0; e2 < 16; e2++) \
                acc[e2] = fmaf(wv, win[e2 + o], acc[e2]); } }
        LOADROW(-6) APPLY(3,0)
        LOADROW(-4) APPLY(2,0)
        LOADROW(-3) APPLY(3,1)
        LOADROW(-2) APPLY(1,0) APPLY(2,1)
        LOADROW(-1) APPLY(1,1)
        LOADROW(0)  APPLY(1,2) APPLY(2,2) APPLY(3,2)
        LOADROW(1)  APPLY(1,3)
        LOADROW(2)  APPLY(1,4) APPLY(2,3)
        LOADROW(3)  APPLY(3,3)
        LOADROW(4)  APPLY(2,4)
        LOADROW(6)  APPLY(3,4)
#undef LOADROW
#undef APPLY
    } else {
        const float4* p4 = (const float4*)(xp + y * 128 + x0);
#pragma unroll
        for (int i = 0; i < 4; i++) {
            float4 v = p4[i];
            acc[i*4] = v.x; acc[i*4+1] = v.y; acc[i*4+2] = v.z; acc[i*4+3] = v.w;
        }
    }
    float ys = y * (4.0f / 127.0f);
    int yi0 = (int)ys; if (yi0 > 4) yi0 = 4;
    int yi1 = yi0 + 1; if (yi1 > 4) yi1 = 4;
    float wy = ys - (float)yi0;
    float ry0 = kt[yi0*5+0] * (1.f-wy) + kt[yi1*5+0] * wy;
    float ry1 = kt[yi0*5+1] * (1.f-wy) + kt[yi1*5+1] * wy;
    float ry2 = kt[yi0*5+2] * (1.f-wy) + kt[yi1*5+2] * wy;
    float ry3 = kt[yi0*5+3] * (1.f-wy) + kt[yi1*5+3] * wy;
    float ry4 = kt[yi0*5+4] * (1.f-wy) + kt[yi1*5+4] * wy;
    float res[16];
#pragma unroll
    for (int e = 0; e < 16; e++) {
        int x = x0 + e;
        float xs2 = x * (4.0f / 127.0f);
        int xi0 = (int)xs2; if (xi0 > 4) xi0 = 4;
        float wx = xs2 - (float)xi0;
        float a = xi0==0 ? ry0 : xi0==1 ? ry1 : xi0==2 ? ry2 : xi0==3 ? ry3 : ry4;
        float bs = xi0>=3 ? ry4 : (xi0==2 ? ry3 : (xi0==1 ? ry2 : ry1));
        float kv = a + (bs - a) * wx;
        res[e] = acc[e] * (1.0f + kv);
    }
    float* op = out2f + (size_t)(b * 64 + c) * HW + (size_t)y * 128 + x0;
#pragma unroll
    for (int i = 0; i < 4; i++) {
        float4 v = { res[i*4], res[i*4+1], res[i*4+2], res[i*4+3] };
        ((float4*)op)[i] = v;
    }
}

// ---------------- final: att0 * sesc * outb * A1 (NHWC bf16 -> NCHW f32) ----------------
__global__ void final_kernel(const unsigned short* __restrict__ att0,
                             const float* __restrict__ scale,
                             const unsigned short* __restrict__ outb,
                             const unsigned short* __restrict__ a1,
                             float* __restrict__ o) {
    __shared__ float t[64][65];
    int b = blockIdx.y;
    int p0 = blockIdx.x * 64;
    int tid = threadIdx.x;
    for (int e = tid; e < 4096; e += 256) {
        int px = e >> 6, c = e & 63;
        size_t idx = ((size_t)b * HW + p0 + px) * 64 + c;
        t[c][px] = bf2f(att0[idx]) * scale[b * 64 + c] * bf2f(outb[idx]) * bf2f(a1[idx]);
    }
    __syncthreads();
    for (int e = tid; e < 4096; e += 256) {
        int c = e >> 6, px = e & 63;
        o[((size_t)b * 64 + c) * HW + p0 + px] = t[c][px];
    }
}

extern "C" void kernel_launch(void* const* d_in, const int* in_sizes, int n_in,
                              void* d_out, int out_size, void* d_ws, size_t ws_size,
                              hipStream_t stream) {
    const float* x1      = (const float*)d_in[0];
    const float* kk      = (const float*)d_in[1];
    const float* conv1_w = (const float*)d_in[2];
    const float* conv1_g = (const float*)d_in[3];
    const float* conv1_b = (const float*)d_in[4];
    const float* conv2_w = (const float*)d_in[5];
    const float* conv2_g = (const float*)d_in[6];
    const float* conv2_b = (const float*)d_in[7];
    const float* conv_w  = (const float*)d_in[8];
    const float* conv_bias = (const float*)d_in[9];
    const float* c0_w  = (const float*)d_in[10];
    const float* c0_g  = (const float*)d_in[11];
    const float* c0_b  = (const float*)d_in[12];
    const float* attc_w = (const float*)d_in[13];
    const float* attc_g = (const float*)d_in[14];
    const float* attc_b = (const float*)d_in[15];
    const float* c05_w = (const float*)d_in[16];
    const float* c05_g = (const float*)d_in[17];
    const float* c05_b = (const float*)d_in[18];
    const float* conv0a_w = (const float*)d_in[19];
    const float* conv0a_g = (const float*)d_in[20];
    const float* conv0a_b = (const float*)d_in[21];
    const float* conv0b_w = (const float*)d_in[22];
    const float* conv0b_g = (const float*)d_in[23];
    const float* conv0b_b = (const float*)d_in[24];
    const float* se_w1 = (const float*)d_in[25];
    const float* se_w2 = (const float*)d_in[26];

    // ---- workspace: 16 MB units ----
    const size_t U = (size_t)8 * HW * 64 * 2;           // 16,777,216 B
    unsigned char* P = (unsigned char*)d_ws;
    unsigned short* x1a        = (unsigned short*)(P + 0 * U);
    unsigned short* x1b        = (unsigned short*)(P + 1 * U);
    unsigned short* att0_bf    = (unsigned short*)(P + 2 * U);
    unsigned short* fuse_bf    = (unsigned short*)(P + 3 * U);
    unsigned short* f1_bf      = (unsigned short*)(P + 4 * U);
    float*          f2         = (float*)         (P + 5 * U);   // 2 units, f32 NCHW
    unsigned short* f2_bf      = (unsigned short*)(P + 7 * U);
    unsigned short* A1_bf      = (unsigned short*)(P + 8 * U);
    unsigned short* eadd_bf    = (unsigned short*)(P + 9 * U);
    unsigned short* out1_bf    = (unsigned short*)(P + 10 * U);
    unsigned short* A12_bf     = (unsigned short*)(P + 11 * U);
    // aliases by liveness:
    float*          out2_f32    = (float*)(P + 0 * U);   // units 0-1 (after triple)
    unsigned short* out2_bf     = fuse_bf;               // after 3x3#1
    unsigned short* oc_bf       = f1_bf;                 // after 3x3#3
    unsigned short* fuseout2_bf = x1a;                   // after repack64
    unsigned short* eout2_bf    = x1b;                   // after 5x5#2 input read... (unit1)
    unsigned short* out2fin_bf  = eadd_bf;               // after 3x3#2
    unsigned short* outa_bf     = fuse_bf;               // after 5x5#1 (out2_bf dead)
    unsigned short* outb_bf     = f1_bf;                 // after 5x5#2 (oc dead)

    unsigned char* W0 = P + 12 * U;
    unsigned short* Wp1   = (unsigned short*)(W0);             // 4*12*64*8*2 = 49152
    unsigned short* Wc0   = (unsigned short*)(W0 + 49152);     // 9*8KB = 73728
    unsigned short* Wattc = (unsigned short*)(W0 + 122880);    // 73728
    unsigned short* Wc05  = (unsigned short*)(W0 + 196608);    // 25*8KB = 204800
    unsigned short* Wc0a  = (unsigned short*)(W0 + 401408);    // 16384
    unsigned short* Wc0b  = (unsigned short*)(W0 + 417792);    // 73728
    float* va   = (float*)(W0 + 491520);   // 1024
    float* cva  = va + 1024;               // 512
    float* part = cva + 512;               // 8*16*64
    float* sesc = part + 8192;             // 512

    const dim3 gconv(128, 8);   // 16 y-tiles x 8 x-tiles, batch

    // ---- prep ----
    mean_hw_kernel<<<1024, 256, 0, stream>>>(x1, va);
    convva_kernel<<<1, 512, 0, stream>>>(va, conv_w, cva);
    repack_x1_kernel<<<dim3(256, 8), 256, 0, stream>>>(x1, x1a, x1b);
    prep_w1x1_kernel<<<32, 256, 0, stream>>>(conv_w,  Wp1, 0);
    prep_w1x1_kernel<<<32, 256, 0, stream>>>(conv1_w, Wp1, 64);
    prep_w1x1_kernel<<<32, 256, 0, stream>>>(conv2_w, Wp1, 128);
    prep_wtap_kernel<<<144, 256, 0, stream>>>(c0_w,    Wc0,   3);
    prep_wtap_kernel<<<144, 256, 0, stream>>>(attc_w,  Wattc, 3);
    prep_wtap_kernel<<<400, 256, 0, stream>>>(c05_w,   Wc05,  5);
    prep_w16_kernel<<<32, 256, 0, stream>>>(conv0a_w, Wc0a);
    prep_wtap_kernel<<<144, 256, 0, stream>>>(conv0b_w, Wc0b, 3);

    // ---- merged 1x1 triple over x1 ----
    conv1x1_triple<<<gconv, 256, 0, stream>>>(x1a, x1b, Wp1, cva, conv_bias,
        conv1_g, conv1_b, conv2_g, conv2_b, kk, fuse_bf, att0_bf, f1_bf, f2, f2_bf);

    att_mean_part<<<dim3(16, 8), 256, 0, stream>>>(att0_bf, part);
    se_mlp_kernel<<<1, 512, 0, stream>>>(part, se_w1, se_w2, sesc);

    // ---- dyndil: f2 (f32 NCHW) -> out2_f32 (f32 NCHW, units 0-1; x1a/x1b dead) ----
    dyndil_kernel<<<2048, 256, 0, stream>>>(f2, kk, out2_f32);

    // ---- 3x3 chain ----
    conv_mfma<3><<<gconv, 256, 0, stream>>>(fuse_bf, Wc0,
        c0_g, c0_b, kk, nullptr, nullptr, eadd_bf, nullptr, 0);
    conv_mfma<3><<<gconv, 256, 0, stream>>>(eadd_bf, Wattc,
        attc_g, attc_b, kk, nullptr, nullptr, A1_bf, nullptr, 1);
    conv_mfma<3><<<gconv, 256, 0, stream>>>(f1_bf, Wc0,
        c0_g, c0_b, kk, nullptr, nullptr, out1_bf, nullptr, 2);
    conv_mfma<3><<<gconv, 256, 0, stream>>>(out1_bf, Wattc,
        attc_g, attc_b, kk, A1_bf, nullptr, A12_bf, nullptr, 6);

    // ---- repack dyndil output to NHWC bf16 (fuse unit now dead) ----
    repack64_kernel<<<dim3(256, 8), 256, 0, stream>>>(out2_f32, out2_bf);

    // ---- 5x5 chain ----
    conv_mfma<5><<<gconv, 256, 0, stream>>>(out2_bf, Wc05,
        c05_g, c05_b, kk, A12_bf, nullptr, oc_bf, fuseout2_bf, 4);
    conv_mfma<5><<<gconv, 256, 0, stream>>>(fuseout2_bf, Wc05,
        c05_g, c05_b, kk, oc_bf, f2_bf, eout2_bf, nullptr, 5);
    conv_mfma<5><<<gconv, 256, 0, stream>>>(eout2_bf, Wc05,
        c05_g, c05_b, kk, nullptr, nullptr, out2fin_bf, nullptr, 0);

    // ---- head ----
    conv_mfma1x1<<<gconv, 256, 0, stream>>>(out1_bf, out2fin_bf, Wc0a,
        conv0a_g, conv0a_b, outa_bf);
    conv_mfma<3><<<gconv, 256, 0, stream>>>(outa_bf, Wc0b,
        conv0b_g, conv0b_b, kk, nullptr, nullptr, outb_bf, nullptr, 0);
    final_kernel<<<dim3(256, 8), 256, 0, stream>>>(att0_bf, sesc, outb_bf, A1_bf, (float*)d_out);
}